// Round 2
// baseline (523.641 us; speedup 1.0000x reference)
//
#include <hip/hip_runtime.h>

// Voxel pooling v3: LDS-staged coarse binning + fused bin/accumulate.
// v2 bug: bin = v>>7 = (b,y) -> only 128 bins active per scan block (b is
// constant within a block), lambda=16 > CAP=15 -> ~150k spills overflowed
// SPILLCAP -> dropped points (absmax 7.9). Fix: bin = v & 255 = (y&1,x),
// uniform across 256 bins within every block (x,y random per point), lambda=8.
// Pipeline:
//   memset(spillcnt)
//   pre_kernel : scan blocks bin 2048 pts each into 256 LDS bins (LDS atomics),
//                stream bin table out as full-line writes to staging[bin][block];
//                + tail blocks do the ctx transpose.
//   acc_kernel : one block per bin (128 voxels, stride-256 in v); accumulates
//                dep*ctx_t[row] into a 40KB LDS out-slice (LDS f32 atomics),
//                scatters 320B/voxel coalesced chunks to out.
//   spill_kernel: exact fixup for rare slice overflows (~1.6k entries expected).

namespace {
constexpr int NVX = 128, NVY = 128, C = 80;
constexpr int B = 2, N = 6, D = 112, H = 16, W = 44;
constexpr int HW    = H * W;             // 704
constexpr int BN    = B * N;             // 12
constexpr int DHW   = D * HW;            // 78848
constexpr int NDHW  = N * DHW;           // 473088 (points per batch)
constexpr int TOTAL = B * NDHW;          // 946176
constexpr int NVOX  = B * NVY * NVX;     // 32768

constexpr int NBIN  = 256;               // bin = v & 255 = (y&1)*128 + x
constexpr int VPB   = NVOX / NBIN;       // 128 voxels per bin (vl = v>>8)
constexpr int SLOT  = 16;                // slice stride in int2 (128B = 2 lines)
constexpr int CAP   = 15;                // slots 0..14 data, slot 15 = count
constexpr int PTS_PER_BLK = 2048;        // 8 points/thread * 256 threads
constexpr int SCAN_BLOCKS = TOTAL / PTS_PER_BLK;   // 462 (exact; b-split at 231)
constexpr int TR_BLOCKS   = BN * (C / 16) * (HW / 64); // 660
constexpr int PRE_BLOCKS  = SCAN_BLOCKS + TR_BLOCKS;   // 1122
constexpr int SPILLCAP = 65536;
}

// ---- 1. fused: LDS binning (blocks < SCAN_BLOCKS) | tiled transpose (rest) ----
__global__ __launch_bounds__(256) void pre_kernel(
    const int*   __restrict__ geom, const float* __restrict__ depth,
    const float* __restrict__ ctx,  float* __restrict__ ctx_t,
    int2* __restrict__ staging, int* __restrict__ spillcnt,
    int2* __restrict__ spill)
{
    __shared__ int2  stage[NBIN * SLOT];   // 32 KB
    __shared__ int   bcnt[NBIN];           // 1 KB
    __shared__ float tile[16 * 68];        // transpose scratch

    if (blockIdx.x < SCAN_BLOCKS) {
        const int t = threadIdx.x;
        bcnt[t] = 0;                       // NBIN == blockDim.x == 256
        __syncthreads();

        const int p0 = blockIdx.x * PTS_PER_BLK + t * 8;
        const int4* g4 = (const int4*)(geom + (size_t)3 * p0);  // 96B, aligned
        int4 q[6];
        #pragma unroll
        for (int i = 0; i < 6; ++i) q[i] = g4[i];
        const float4 d0 = *(const float4*)(depth + p0);
        const float4 d1 = *(const float4*)(depth + p0 + 4);
        const int xs[8] = {q[0].x, q[0].w, q[1].z, q[2].y,
                           q[3].x, q[3].w, q[4].z, q[5].y};
        const int ys[8] = {q[0].y, q[1].x, q[1].w, q[2].z,
                           q[3].y, q[4].x, q[4].w, q[5].z};
        const float ds[8] = {d0.x, d0.y, d0.z, d0.w, d1.x, d1.y, d1.z, d1.w};

        #pragma unroll
        for (int u = 0; u < 8; ++u) {
            const int x = xs[u], y = ys[u];
            if ((unsigned)x >= (unsigned)NVX || (unsigned)y >= (unsigned)NVY) continue;
            const int p   = p0 + u;
            const int b   = (p >= NDHW) ? 1 : 0;          // B == 2
            const int v   = (b * NVY + y) * NVX + x;
            const int bn  = (unsigned)p / (unsigned)DHW;
            const int hw  = (unsigned)p % (unsigned)HW;
            const int key = (v << 14) | (bn * HW + hw);   // v:15b | row:14b
            const int bin = v & 255;                      // uniform per block!
            const int idx = atomicAdd(&bcnt[bin], 1);     // LDS atomic, cheap
            if (idx < CAP) {
                stage[bin * SLOT + idx] = make_int2(key, __float_as_int(ds[u]));
            } else {
                int s = atomicAdd(spillcnt, 1);
                if (s < SPILLCAP) spill[s] = make_int2(key, __float_as_int(ds[u]));
            }
        }
        __syncthreads();
        stage[t * SLOT + CAP].x = bcnt[t];   // embed count in slot 15
        __syncthreads();

        // stream out: 2048 int4, coalesced; 8-thread groups write one 128B
        // slice each -> every global write is a full 64B line.
        const int4* src = (const int4*)stage;
        int4* dst = (int4*)staging;
        #pragma unroll
        for (int k = 0; k < 8; ++k) {
            const int i = k * 256 + t;            // 0..2047
            const int bin = i >> 3, part = i & 7; // 8 int4 per slice
            dst[((size_t)bin * SCAN_BLOCKS + blockIdx.x) * 8 + part] = src[i];
        }
    } else {
        // transpose ctx (bn, c, hw) -> ctx_t (bn*HW + hw, c), 16c x 64hw tiles
        const int tb  = blockIdx.x - SCAN_BLOCKS;
        const int bn  = tb / 55;
        const int rem = tb % 55;
        const int c0  = (rem / 11) * 16;
        const int hw0 = (rem % 11) * 64;
        const int t = threadIdx.x;
        const int cl = t >> 6, hwl = t & 63;
        #pragma unroll
        for (int r = 0; r < 4; ++r) {
            const int c = r * 4 + cl;
            tile[c * 68 + hwl] =
                ctx[(size_t)(bn * C + c0 + c) * HW + hw0 + hwl];
        }
        __syncthreads();
        const int cr = t & 15, hwr = t >> 4;
        #pragma unroll
        for (int r = 0; r < 4; ++r) {
            const int hw = r * 16 + hwr;
            ctx_t[(size_t)(bn * HW + hw0 + hw) * C + c0 + cr] =
                tile[cr * 68 + hw];
        }
    }
}

// ---- 2. fused bin + accumulate: one block per bin, out-slice in LDS ----
__global__ __launch_bounds__(1024) void acc_kernel(
    const int2* __restrict__ staging, const float* __restrict__ ctx_t,
    float* __restrict__ out)
{
    __shared__ float acc[VPB * C];   // 128 voxels * 80 ch = 40 KB
    const int bin = blockIdx.x;
    const int t   = threadIdx.x;
    #pragma unroll
    for (int i = t; i < VPB * C; i += 1024) acc[i] = 0.f;
    __syncthreads();

    const int wave = t >> 6, lane = t & 63;
    // 462 slices per bin, processed 2 per wave-iteration (A in lanes 0..15,
    // B in lanes 16..31) -> two independent load chains, software-pipelined.
    for (int g = wave; g < SCAN_BLOCKS / 2; g += 16) {
        int2 e;
        const size_t base = ((size_t)bin * SCAN_BLOCKS + g * 2) * SLOT;
        if (lane < 32) e = staging[base + lane];   // 512B coalesced (2 slices)
        int nA = __shfl(e.x, 15); nA = nA < CAP ? nA : CAP;
        int nB = __shfl(e.x, 31); nB = nB < CAP ? nB : CAP;
        const int m = nA > nB ? nA : nB;
        int kA = 0, kB = 0; float dA = 0.f, dB = 0.f;
        float pa = 0.f, pb = 0.f, qa = 0.f, qb = 0.f;
        if (nA > 0) {
            kA = __shfl(e.x, 0); dA = __int_as_float(__shfl(e.y, 0));
            const float* c = ctx_t + (size_t)(kA & 16383) * C;
            pa = c[lane]; pb = (lane < 16) ? c[64 + lane] : 0.f;
        }
        if (nB > 0) {
            kB = __shfl(e.x, 16); dB = __int_as_float(__shfl(e.y, 16));
            const float* c = ctx_t + (size_t)(kB & 16383) * C;
            qa = c[lane]; qb = (lane < 16) ? c[64 + lane] : 0.f;
        }
        for (int j = 0; j < m; ++j) {
            const int   ckA = kA, ckB = kB;
            const float cdA = dA, cpa = pa, cpb = pb;
            const float cdB = dB, cqa = qa, cqb = qb;
            if (j + 1 < nA) {   // prefetch next A entry's ctx row
                kA = __shfl(e.x, j + 1); dA = __int_as_float(__shfl(e.y, j + 1));
                const float* c = ctx_t + (size_t)(kA & 16383) * C;
                pa = c[lane]; pb = (lane < 16) ? c[64 + lane] : 0.f;
            }
            if (j + 1 < nB) {   // prefetch next B entry's ctx row
                kB = __shfl(e.x, 16 + j + 1); dB = __int_as_float(__shfl(e.y, 16 + j + 1));
                const float* c = ctx_t + (size_t)(kB & 16383) * C;
                qa = c[lane]; qb = (lane < 16) ? c[64 + lane] : 0.f;
            }
            if (j < nA) {
                const int vl = (ckA >> 22) & 127;     // vl = v>>8
                atomicAdd(&acc[vl * C + lane], cdA * cpa);
                if (lane < 16) atomicAdd(&acc[vl * C + 64 + lane], cdA * cpb);
            }
            if (j < nB) {
                const int vl = (ckB >> 22) & 127;
                atomicAdd(&acc[vl * C + lane], cdB * cqa);
                if (lane < 16) atomicAdd(&acc[vl * C + 64 + lane], cdB * cqb);
            }
        }
    }
    __syncthreads();
    // scatter: voxel vl -> v = (vl>>6)*16384 + ((vl&63)*2 + (bin>>7))*128 + (bin&127)
    const int ybit = bin >> 7, x = bin & 127;
    const float4* a4 = (const float4*)acc;
    for (int i = t; i < VPB * (C / 4); i += 1024) {
        const int vl   = i / (C / 4);
        const int part = i % (C / 4);
        const int b = vl >> 6, y = ((vl & 63) << 1) | ybit;
        float4* o4 = (float4*)(out + (size_t)((b * NVY + y) * NVX + x) * C);
        o4[part] = a4[i];
    }
}

// ---- 3. spill fixup (runs after acc_kernel; exact, ~1.6k entries expected) ----
__global__ __launch_bounds__(256) void spill_kernel(
    const int* __restrict__ spillcnt, const int2* __restrict__ spill,
    const float* __restrict__ ctx_t, float* __restrict__ out)
{
    const int nwaves = gridDim.x * 4;
    const int wave   = blockIdx.x * 4 + (threadIdx.x >> 6);
    const int lane   = threadIdx.x & 63;
    int cnt = *spillcnt;
    if (cnt > SPILLCAP) cnt = SPILLCAP;
    for (int i = wave; i < cnt; i += nwaves) {
        const int2 e = spill[i];
        const int v   = e.x >> 14;          // key < 2^29, positive
        const int row = e.x & 16383;
        const float dep = __int_as_float(e.y);
        const float* c = ctx_t + (size_t)row * C;
        float* o = out + (size_t)v * C;
        unsafeAtomicAdd(o + lane, dep * c[lane]);
        if (lane < C - 64) unsafeAtomicAdd(o + 64 + lane, dep * c[64 + lane]);
    }
}

extern "C" void kernel_launch(void* const* d_in, const int* in_sizes, int n_in,
                              void* d_out, int out_size, void* d_ws, size_t ws_size,
                              hipStream_t stream) {
    const int*   geom  = (const int*)d_in[0];
    const float* depth = (const float*)d_in[1];
    const float* ctx   = (const float*)d_in[2];
    float*       out   = (float*)d_out;

    // Workspace (~18.4 MB, all segments 256B-multiple):
    char* ws = (char*)d_ws;
    int2* staging  = (int2*)ws; ws += (size_t)SCAN_BLOCKS * NBIN * SLOT * 8; // 15,138,816
    int2* spill    = (int2*)ws; ws += (size_t)SPILLCAP * 8;                  // 524,288
    int*  spillcnt = (int*)ws;  ws += 256;
    float* ctx_t   = (float*)ws;                                             // 2,703,360

    hipMemsetAsync(spillcnt, 0, 256, stream);

    pre_kernel  <<<dim3(PRE_BLOCKS), dim3(256),  0, stream>>>(
                    geom, depth, ctx, ctx_t, staging, spillcnt, spill);
    acc_kernel  <<<dim3(NBIN),       dim3(1024), 0, stream>>>(staging, ctx_t, out);
    spill_kernel<<<dim3(64),         dim3(256),  0, stream>>>(spillcnt, spill, ctx_t, out);
}